// Round 16
// baseline (126.568 us; speedup 1.0000x reference)
//
#include <hip/hip_runtime.h>
#include <hip/hip_bf16.h>

#define NUM_NODES 50000
#define NODE_DIM 32
#define EDGE_DIM 7
#define HIDDEN_DIM 64
#define NUM_EDGES 200000

typedef __attribute__((ext_vector_type(8))) short bf16x8;
typedef __attribute__((ext_vector_type(4))) float f32x4;
typedef _Float16 h2v __attribute__((ext_vector_type(2)));

__device__ inline unsigned f2bf(float f) {
    union { float f; unsigned u; } x; x.f = f;
    return (x.u + 0x7FFFu + ((x.u >> 16) & 1u)) >> 16;   // RNE
}
__device__ inline unsigned pack2bf(float a, float b) {
    return f2bf(a) | (f2bf(b) << 16);
}
__device__ inline h2v u2h(unsigned u) {
    union { unsigned u; h2v h; } c; c.u = u; return c.h;
}
__device__ inline unsigned h2u(h2v h) {
    union { h2v h; unsigned u; } c; c.h = h; return c.u;
}
__device__ inline unsigned packh2(float a, float b) {
    h2v h; h[0] = (_Float16)a; h[1] = (_Float16)b; return h2u(h);
}

// ---------------------------------------------------------------------------
// K_P: per-lane B fragments for the classifier GEMM (bf16, verified r4+).
// ---------------------------------------------------------------------------
__global__ __launch_bounds__(256) void k_prep(const float* __restrict__ w_e1,
                                              const float* __restrict__ b_e1,
                                              ushort* __restrict__ bfrag) {
    int u = blockIdx.x * blockDim.x + threadIdx.x;
    if (u < 5 * 4 * 64 * 8) {
        int j     = u & 7;
        int lane  = (u >> 3) & 63;
        int ntile = (u >> 9) & 3;
        int kstep = u >> 11;
        int k = kstep * 32 + (lane >> 4) * 8 + j;
        int o = ntile * 16 + (lane & 15);
        float v = (k < 135) ? w_e1[k * 64 + o] : ((k == 135) ? b_e1[o] : 0.f);
        bfrag[u] = (ushort)f2bf(v);
    }
}

// ---------------------------------------------------------------------------
// K_A: agg[n][o] = conv_bias[o] + sum_i x[n][i] * root_w[i][o]   (verified)
// ---------------------------------------------------------------------------
__global__ __launch_bounds__(256) void k_init2(const float* __restrict__ x,
                                               const float* __restrict__ root_w,
                                               const float* __restrict__ conv_bias,
                                               float* __restrict__ agg) {
    __shared__ float rw[NODE_DIM * HIDDEN_DIM];   // 8KB
    __shared__ float cb[HIDDEN_DIM];
    __shared__ float xS[128 * NODE_DIM];          // 16KB
    for (int t = threadIdx.x; t < NODE_DIM * HIDDEN_DIM; t += 256) rw[t] = root_w[t];
    if (threadIdx.x < HIDDEN_DIM) cb[threadIdx.x] = conv_bias[threadIdx.x];
    const int nb = blockIdx.x * 128;
    {
        const float4* xg = (const float4*)x;
        float4* xs4 = (float4*)xS;
        #pragma unroll
        for (int r = 0; r < 4; ++r) {
            int t = r * 256 + threadIdx.x;
            int gi = nb * (NODE_DIM / 4) + t;
            xs4[t] = (gi < NUM_NODES * (NODE_DIM / 4)) ? xg[gi] : make_float4(0.f, 0.f, 0.f, 0.f);
        }
    }
    __syncthreads();
    const int lane = threadIdx.x & 63;
    const int w    = threadIdx.x >> 6;
    for (int r = 0; r < 32; ++r) {
        const int n = nb + w * 32 + r;
        if (n >= NUM_NODES) break;                 // wave-uniform
        float acc = cb[lane];
        const float* xr = &xS[(w * 32 + r) * NODE_DIM];
        #pragma unroll
        for (int i = 0; i < NODE_DIM; ++i)
            acc = fmaf(xr[i], rw[i * HIDDEN_DIM + lane], acc);
        agg[n * HIDDEN_DIM + lane] = acc;
    }
}

// ---------------------------------------------------------------------------
// K_B v11: r15's packed-f16 MLP with weights loaded ONCE per p (r15 limiter
// was the LDS pipe: 96 ds_read_b128/group, 64 of them weight re-reads from
// the half-split). Now: loop p4 -> pp, weights 2 b128 per p, all 8 edges in
// the innermost loop. LDS/group: 64 b128 (32 W + 32 X). Cost: evR[8][7]+
// xr[8] pushes VGPR ~110 (16 waves/CU) — acceptable, the 72-op inner body
// per weight load has wide ILP.
//  - native h2v ops: a*b+t -> v_pk_fma_f16, __builtin_elementwise_max ->
//    v_pk_max_f16, fdot2 folds the relu'd pair into f32 acc (r15-proven);
//  - staging, scatter, grid 1024x512: r15-verbatim.
// ---------------------------------------------------------------------------
#define MBX 8
__global__ __launch_bounds__(512) void k_msg11(const int* __restrict__ ei,
                                               const float* __restrict__ ea,
                                               const float* __restrict__ x,
                                               const float* __restrict__ w_nn,
                                               const float* __restrict__ b_nn,
                                               float* __restrict__ agg) {
    __shared__ uint4    wAu[16 * 64];          // 16KB  (k0..k3 pairs)
    __shared__ uint4    wBu[16 * 64];          // 16KB  (k4..k6 + bias pairs)
    __shared__ unsigned xHu[8][MBX][16];       // 4KB   (h2v i-pairs)
    __shared__ float    eS[8][MBX][8];         // 2KB
    for (int c = threadIdx.x; c < 16 * 64; c += 512) {
        const int p = c >> 6, o = c & 63;
        const int c0 = (2 * p) * 64 + o, c1 = c0 + 64;
        uint4 a, b;
        a.x = packh2(w_nn[c0],            w_nn[c1]);
        a.y = packh2(w_nn[2048 + c0],     w_nn[2048 + c1]);
        a.z = packh2(w_nn[2 * 2048 + c0], w_nn[2 * 2048 + c1]);
        a.w = packh2(w_nn[3 * 2048 + c0], w_nn[3 * 2048 + c1]);
        b.x = packh2(w_nn[4 * 2048 + c0], w_nn[4 * 2048 + c1]);
        b.y = packh2(w_nn[5 * 2048 + c0], w_nn[5 * 2048 + c1]);
        b.z = packh2(w_nn[6 * 2048 + c0], w_nn[6 * 2048 + c1]);
        b.w = packh2(b_nn[c0],            b_nn[c1]);
        wAu[c] = a; wBu[c] = b;
    }
    __syncthreads();

    const int lane   = threadIdx.x & 63;
    const int ws     = threadIdx.x >> 6;
    const int wave   = (blockIdx.x * blockDim.x + threadIdx.x) >> 6;
    const int nwaves = (gridDim.x * blockDim.x) >> 6;

    for (int e0 = wave * MBX; e0 < NUM_EDGES; e0 += nwaves * MBX) {
        // NUM_EDGES % 8 == 0, no tail.
        int sD[MBX];
        #pragma unroll
        for (int m = 0; m < MBX; ++m)
            sD[m] = __builtin_amdgcn_readfirstlane(ei[NUM_EDGES + e0 + m]);

        // stage x rows as packed h2v i-pairs + ea floats (r15-verbatim)
        {
            const int m  = lane >> 3;
            const int q4 = lane & 7;
            const int s  = ei[e0 + m];
            const float4 xv = *(const float4*)(x + (size_t)s * NODE_DIM + q4 * 4);
            xHu[ws][m][2 * q4 + 0] = packh2(xv.x, xv.y);
            xHu[ws][m][2 * q4 + 1] = packh2(xv.z, xv.w);
            if (lane < MBX * EDGE_DIM)
                eS[ws][lane / EDGE_DIM][lane % EDGE_DIM] = ea[(size_t)e0 * EDGE_DIM + lane];
        }
        // wave-coherent LDS write->read; compiler inserts waits (r2-r4 proven).

        // replicated ea per-k for all 8 edges (56 VGPR)
        h2v evR[MBX][7];
        #pragma unroll
        for (int j = 0; j < MBX; ++j) {
            const float4* e4 = (const float4*)&eS[ws][j][0];
            const float4 a0 = e4[0], a1 = e4[1];   // a1.w unused
            evR[j][0] = (h2v)((_Float16)a0.x);
            evR[j][1] = (h2v)((_Float16)a0.y);
            evR[j][2] = (h2v)((_Float16)a0.z);
            evR[j][3] = (h2v)((_Float16)a0.w);
            evR[j][4] = (h2v)((_Float16)a1.x);
            evR[j][5] = (h2v)((_Float16)a1.y);
            evR[j][6] = (h2v)((_Float16)a1.z);
        }

        float acc[MBX];
        #pragma unroll
        for (int m = 0; m < MBX; ++m) acc[m] = 0.f;

        #pragma unroll 2
        for (int p4 = 0; p4 < 4; ++p4) {
            uint4 xr[MBX];
            #pragma unroll
            for (int j = 0; j < MBX; ++j)
                xr[j] = *(const uint4*)&xHu[ws][j][p4 * 4];      // 8 b128 broadcasts
            #pragma unroll
            for (int pp = 0; pp < 4; ++pp) {
                const int p = p4 * 4 + pp;
                const uint4 wa = wAu[p * 64 + lane];             // 2 b128, once per p
                const uint4 wb = wBu[p * 64 + lane];
                #pragma unroll
                for (int j = 0; j < MBX; ++j) {
                    h2v t = u2h(wb.w);                           // bias pair
                    t = evR[j][0] * u2h(wa.x) + t;               // v_pk_fma_f16
                    t = evR[j][1] * u2h(wa.y) + t;
                    t = evR[j][2] * u2h(wa.z) + t;
                    t = evR[j][3] * u2h(wa.w) + t;
                    t = evR[j][4] * u2h(wb.x) + t;
                    t = evR[j][5] * u2h(wb.y) + t;
                    t = evR[j][6] * u2h(wb.z) + t;
                    t = __builtin_elementwise_max(t, (h2v)((_Float16)0.f)); // v_pk_max
                    const unsigned xp = (pp == 0) ? xr[j].x : (pp == 1) ? xr[j].y
                                      : (pp == 2) ? xr[j].z : xr[j].w;
                    acc[j] = __builtin_amdgcn_fdot2(t, u2h(xp), acc[j], false);
                }
            }
        }

        #pragma unroll
        for (int m = 0; m < MBX; ++m)
            atomicAdd(&agg[(size_t)sD[m] * HIDDEN_DIM + lane], acc[m]);
    }
}

// ---------------------------------------------------------------------------
// K_C v3: classifier as bf16 MFMA GEMM (verbatim, passing since round 4).
// ---------------------------------------------------------------------------
#define ASTRIDE 168
__global__ __launch_bounds__(256) void k_edge3(const int* __restrict__ ei,
                                               const float* __restrict__ ea,
                                               const float* __restrict__ agg,
                                               const ushort* __restrict__ bfrag,
                                               const float* __restrict__ w_e2,
                                               const float* __restrict__ b_e2,
                                               float* __restrict__ out) {
    __shared__ ushort aS[64 * ASTRIDE];   // 21504B
    __shared__ ushort bS[5 * 4 * 64 * 8]; // 20480B
    __shared__ float  w2S[128];
    {
        const uint4* g = (const uint4*)bfrag;
        uint4* s = (uint4*)bS;
        for (int t = threadIdx.x; t < 1280; t += 256) s[t] = g[t];
        if (threadIdx.x < 128) w2S[threadIdx.x] = w_e2[threadIdx.x];
    }
    const int e0 = blockIdx.x * 64;
    {
        const int el = threadIdx.x >> 2;
        const int q  = threadIdx.x & 3;
        const int e  = e0 + el;
        const int src = ei[e], dst = ei[NUM_EDGES + e];
        const float4* ps = (const float4*)(agg + (size_t)src * HIDDEN_DIM + q * 16);
        const float4* pd = (const float4*)(agg + (size_t)dst * HIDDEN_DIM + q * 16);
        unsigned* arow = (unsigned*)(aS + el * ASTRIDE);
        #pragma unroll
        for (int i = 0; i < 4; ++i) {
            float4 s = ps[i];
            arow[q * 8 + i * 2 + 0] = pack2bf(fmaxf(s.x, 0.f), fmaxf(s.y, 0.f));
            arow[q * 8 + i * 2 + 1] = pack2bf(fmaxf(s.z, 0.f), fmaxf(s.w, 0.f));
        }
        #pragma unroll
        for (int i = 0; i < 4; ++i) {
            float4 d = pd[i];
            arow[32 + q * 8 + i * 2 + 0] = pack2bf(fmaxf(d.x, 0.f), fmaxf(d.y, 0.f));
            arow[32 + q * 8 + i * 2 + 1] = pack2bf(fmaxf(d.z, 0.f), fmaxf(d.w, 0.f));
        }
        if (q == 0) {
            float ev[8];
            #pragma unroll
            for (int k = 0; k < EDGE_DIM; ++k) ev[k] = ea[e * EDGE_DIM + k];
            ev[7] = 1.0f;
            #pragma unroll
            for (int i = 0; i < 4; ++i)
                arow[64 + i] = pack2bf(ev[2 * i], ev[2 * i + 1]);
        } else {
            unsigned* z = arow + 64 + q * 4;
            z[0] = 0u; z[1] = 0u; z[2] = 0u; z[3] = 0u;
        }
    }
    __syncthreads();

    const int lane = threadIdx.x & 63;
    const int w    = threadIdx.x >> 6;
    f32x4 acc[4];
    #pragma unroll
    for (int nt = 0; nt < 4; ++nt) acc[nt] = (f32x4){0.f, 0.f, 0.f, 0.f};

    const ushort* arow = aS + (w * 16 + (lane & 15)) * ASTRIDE + (lane >> 4) * 8;
    #pragma unroll
    for (int ks = 0; ks < 5; ++ks) {
        bf16x8 af = *(const bf16x8*)(arow + ks * 32);
        #pragma unroll
        for (int nt = 0; nt < 4; ++nt) {
            bf16x8 bf = *(const bf16x8*)(bS + ((ks * 4 + nt) * 64 + lane) * 8);
            acc[nt] = __builtin_amdgcn_mfma_f32_16x16x32_bf16(af, bf, acc[nt], 0, 0, 0);
        }
    }

    float w20[4], w21[4];
    #pragma unroll
    for (int nt = 0; nt < 4; ++nt) {
        int o = nt * 16 + (lane & 15);
        w20[nt] = w2S[o * 2 + 0];
        w21[nt] = w2S[o * 2 + 1];
    }
    const float bias0 = b_e2[0], bias1 = b_e2[1];
    #pragma unroll
    for (int r = 0; r < 4; ++r) {
        float p0 = 0.f, p1 = 0.f;
        #pragma unroll
        for (int nt = 0; nt < 4; ++nt) {
            float z = fmaxf(acc[nt][r], 0.f);
            p0 = fmaf(z, w20[nt], p0);
            p1 = fmaf(z, w21[nt], p1);
        }
        #pragma unroll
        for (int off = 1; off < 16; off <<= 1) {
            p0 += __shfl_xor(p0, off);
            p1 += __shfl_xor(p1, off);
        }
        if ((lane & 15) == 0) {
            int e = e0 + w * 16 + (lane >> 4) * 4 + r;
            float2 v; v.x = p0 + bias0; v.y = p1 + bias1;
            ((float2*)out)[e] = v;
        }
    }
}

// ---------------------------------------------------------------------------
extern "C" void kernel_launch(void* const* d_in, const int* in_sizes, int n_in,
                              void* d_out, int out_size, void* d_ws, size_t ws_size,
                              hipStream_t stream) {
    const int*   ei        = (const int*)d_in[0];
    const float* edge_attr = (const float*)d_in[1];
    const float* node_emb  = (const float*)d_in[2];
    const float* w_nn      = (const float*)d_in[3];
    const float* b_nn      = (const float*)d_in[4];
    const float* root_w    = (const float*)d_in[5];
    const float* conv_bias = (const float*)d_in[6];
    const float* w_e1      = (const float*)d_in[7];
    const float* b_e1      = (const float*)d_in[8];
    const float* w_e2      = (const float*)d_in[9];
    const float* b_e2      = (const float*)d_in[10];
    float*       out       = (float*)d_out;
    float*       agg       = (float*)d_ws;                       // [N,64] f32 = 12.8 MB
    ushort*      bfrag     = (ushort*)((char*)d_ws + 12800000);  // 20480 B

    // K_P: pre-packed classifier B fragments
    k_prep<<<(5 * 4 * 64 * 8 + 255) / 256, 256, 0, stream>>>(w_e1, b_e1, bfrag);
    // K_A: agg = x @ root_w + conv_bias (fully rewrites region each call)
    k_init2<<<(NUM_NODES + 127) / 128, 256, 0, stream>>>(node_emb, root_w, conv_bias, agg);
    // K_B: fused edge-MLP (packed f16, weights-once) + matvec + scatter
    k_msg11<<<1024, 512, 0, stream>>>(ei, edge_attr, node_emb, w_nn, b_nn, agg);
    // K_C: classifier GEMM
    k_edge3<<<NUM_EDGES / 64, 256, 0, stream>>>(ei, edge_attr, agg, bfrag, w_e2, b_e2, out);
}

// Round 17
// 120.339 us; speedup vs baseline: 1.0518x; 1.0518x over previous
//
#include <hip/hip_runtime.h>
#include <hip/hip_bf16.h>

#define NUM_NODES 50000
#define NODE_DIM 32
#define EDGE_DIM 7
#define HIDDEN_DIM 64
#define NUM_EDGES 200000

#define INIT_BLOCKS ((NUM_NODES + 127) / 128)        // 391
#define PREP_BLOCKS ((5 * 4 * 64 * 8 + 255) / 256)   // 40

typedef __attribute__((ext_vector_type(8))) short bf16x8;
typedef __attribute__((ext_vector_type(4))) float f32x4;
typedef _Float16 h2v __attribute__((ext_vector_type(2)));

__device__ inline unsigned f2bf(float f) {
    union { float f; unsigned u; } x; x.f = f;
    return (x.u + 0x7FFFu + ((x.u >> 16) & 1u)) >> 16;   // RNE
}
__device__ inline unsigned pack2bf(float a, float b) {
    return f2bf(a) | (f2bf(b) << 16);
}
__device__ inline h2v u2h(unsigned u) {
    union { unsigned u; h2v h; } c; c.u = u; return c.h;
}
__device__ inline unsigned h2u(h2v h) {
    union { h2v h; unsigned u; } c; c.h = h; return c.u;
}
__device__ inline unsigned packh2(float a, float b) {
    h2v h; h[0] = (_Float16)a; h[1] = (_Float16)b; return h2u(h);
}

// ---------------------------------------------------------------------------
// K_IP: fused k_init2 + k_prep (both bodies verbatim from r15-passing code;
// block-range guard is wave-uniform). Blocks [0, INIT_BLOCKS) compute
// agg = x @ root_w + conv_bias; blocks [INIT_BLOCKS, +PREP_BLOCKS) build the
// classifier B fragments. Saves one launch/graph node.
// ---------------------------------------------------------------------------
__global__ __launch_bounds__(256) void k_initprep(const float* __restrict__ x,
                                                  const float* __restrict__ root_w,
                                                  const float* __restrict__ conv_bias,
                                                  const float* __restrict__ w_e1,
                                                  const float* __restrict__ b_e1,
                                                  float* __restrict__ agg,
                                                  ushort* __restrict__ bfrag) {
    if (blockIdx.x >= INIT_BLOCKS) {
        // ---- k_prep body (verified r4+) ----
        int u = (blockIdx.x - INIT_BLOCKS) * blockDim.x + threadIdx.x;
        if (u < 5 * 4 * 64 * 8) {
            int j     = u & 7;
            int lane  = (u >> 3) & 63;
            int ntile = (u >> 9) & 3;
            int kstep = u >> 11;
            int k = kstep * 32 + (lane >> 4) * 8 + j;
            int o = ntile * 16 + (lane & 15);
            float v = (k < 135) ? w_e1[k * 64 + o] : ((k == 135) ? b_e1[o] : 0.f);
            bfrag[u] = (ushort)f2bf(v);
        }
        return;
    }
    // ---- k_init2 body (verified r4+) ----
    __shared__ float rw[NODE_DIM * HIDDEN_DIM];   // 8KB
    __shared__ float cb[HIDDEN_DIM];
    __shared__ float xS[128 * NODE_DIM];          // 16KB
    for (int t = threadIdx.x; t < NODE_DIM * HIDDEN_DIM; t += 256) rw[t] = root_w[t];
    if (threadIdx.x < HIDDEN_DIM) cb[threadIdx.x] = conv_bias[threadIdx.x];
    const int nb = blockIdx.x * 128;
    {
        const float4* xg = (const float4*)x;
        float4* xs4 = (float4*)xS;
        #pragma unroll
        for (int r = 0; r < 4; ++r) {
            int t = r * 256 + threadIdx.x;
            int gi = nb * (NODE_DIM / 4) + t;
            xs4[t] = (gi < NUM_NODES * (NODE_DIM / 4)) ? xg[gi] : make_float4(0.f, 0.f, 0.f, 0.f);
        }
    }
    __syncthreads();
    const int lane = threadIdx.x & 63;
    const int w    = threadIdx.x >> 6;
    for (int r = 0; r < 32; ++r) {
        const int n = nb + w * 32 + r;
        if (n >= NUM_NODES) break;                 // wave-uniform
        float acc = cb[lane];
        const float* xr = &xS[(w * 32 + r) * NODE_DIM];
        #pragma unroll
        for (int i = 0; i < NODE_DIM; ++i)
            acc = fmaf(xr[i], rw[i * HIDDEN_DIM + lane], acc);
        agg[n * HIDDEN_DIM + lane] = acc;
    }
}

// ---------------------------------------------------------------------------
// K_B v10b (r15-VERBATIM, best measured 82.4 µs): packed-f16 edge-MLP.
//   a*b+t -> v_pk_fma_f16; __builtin_elementwise_max -> v_pk_max_f16;
//   fdot2 folds relu'd pair into the f32 accumulator.
//  - weights as i-pair planes wAu/wBu (2x16KB LDS, [p*64+lane] b128);
//  - x staged as packed h2v i-pairs; ea replicated per-k, hoisted per edge;
//    8 edges in two halves of 4 (VGPR control);
//  - dst ids -> SGPR, 64-lane atomicAdd scatter, grid 1024x512.
// Plateau note (r12-r16): fp32=103, fdot2=103, pk-f16=82 µs; weight-read
// halving (r16) and LDS staging variants (r13) were neutral — residual is
// latency not pipe-issue; suspects: atomic RMW L2 occupancy, ~10 waves/CU
// effective residency (counter-capped regardless of config).
// ---------------------------------------------------------------------------
#define MBX 8
__global__ __launch_bounds__(512) void k_msg10(const int* __restrict__ ei,
                                               const float* __restrict__ ea,
                                               const float* __restrict__ x,
                                               const float* __restrict__ w_nn,
                                               const float* __restrict__ b_nn,
                                               float* __restrict__ agg) {
    __shared__ uint4    wAu[16 * 64];          // 16KB  (k0..k3 pairs)
    __shared__ uint4    wBu[16 * 64];          // 16KB  (k4..k6 + bias pairs)
    __shared__ unsigned xHu[8][MBX][16];       // 4KB   (h2v i-pairs)
    __shared__ float    eS[8][MBX][8];         // 2KB
    for (int c = threadIdx.x; c < 16 * 64; c += 512) {
        const int p = c >> 6, o = c & 63;
        const int c0 = (2 * p) * 64 + o, c1 = c0 + 64;
        uint4 a, b;
        a.x = packh2(w_nn[c0],            w_nn[c1]);
        a.y = packh2(w_nn[2048 + c0],     w_nn[2048 + c1]);
        a.z = packh2(w_nn[2 * 2048 + c0], w_nn[2 * 2048 + c1]);
        a.w = packh2(w_nn[3 * 2048 + c0], w_nn[3 * 2048 + c1]);
        b.x = packh2(w_nn[4 * 2048 + c0], w_nn[4 * 2048 + c1]);
        b.y = packh2(w_nn[5 * 2048 + c0], w_nn[5 * 2048 + c1]);
        b.z = packh2(w_nn[6 * 2048 + c0], w_nn[6 * 2048 + c1]);
        b.w = packh2(b_nn[c0],            b_nn[c1]);
        wAu[c] = a; wBu[c] = b;
    }
    __syncthreads();

    const int lane   = threadIdx.x & 63;
    const int ws     = threadIdx.x >> 6;
    const int wave   = (blockIdx.x * blockDim.x + threadIdx.x) >> 6;
    const int nwaves = (gridDim.x * blockDim.x) >> 6;

    for (int e0 = wave * MBX; e0 < NUM_EDGES; e0 += nwaves * MBX) {
        // NUM_EDGES % 8 == 0, no tail.
        int sD[MBX];
        #pragma unroll
        for (int m = 0; m < MBX; ++m)
            sD[m] = __builtin_amdgcn_readfirstlane(ei[NUM_EDGES + e0 + m]);

        // stage x rows as packed h2v i-pairs + ea floats
        {
            const int m  = lane >> 3;
            const int q4 = lane & 7;
            const int s  = ei[e0 + m];
            const float4 xv = *(const float4*)(x + (size_t)s * NODE_DIM + q4 * 4);
            xHu[ws][m][2 * q4 + 0] = packh2(xv.x, xv.y);
            xHu[ws][m][2 * q4 + 1] = packh2(xv.z, xv.w);
            if (lane < MBX * EDGE_DIM)
                eS[ws][lane / EDGE_DIM][lane % EDGE_DIM] = ea[(size_t)e0 * EDGE_DIM + lane];
        }
        // wave-coherent LDS write->read; compiler inserts waits (r2-r4 proven).

        float acc[MBX];
        #pragma unroll
        for (int m = 0; m < MBX; ++m) acc[m] = 0.f;

        #pragma unroll
        for (int half = 0; half < 2; ++half) {
            // replicated ea per-k for 4 edges (28 VGPR)
            h2v evR[4][7];
            #pragma unroll
            for (int j = 0; j < 4; ++j) {
                const float4* e4 = (const float4*)&eS[ws][half * 4 + j][0];
                const float4 a0 = e4[0], a1 = e4[1];   // a1.w unused
                evR[j][0] = (h2v)((_Float16)a0.x);
                evR[j][1] = (h2v)((_Float16)a0.y);
                evR[j][2] = (h2v)((_Float16)a0.z);
                evR[j][3] = (h2v)((_Float16)a0.w);
                evR[j][4] = (h2v)((_Float16)a1.x);
                evR[j][5] = (h2v)((_Float16)a1.y);
                evR[j][6] = (h2v)((_Float16)a1.z);
            }

            #pragma unroll 2
            for (int p4 = 0; p4 < 4; ++p4) {
                uint4 xr[4];
                #pragma unroll
                for (int j = 0; j < 4; ++j)
                    xr[j] = *(const uint4*)&xHu[ws][half * 4 + j][p4 * 4];  // b128 broadcast
                #pragma unroll
                for (int pp = 0; pp < 4; ++pp) {
                    const int p = p4 * 4 + pp;
                    const uint4 wa = wAu[p * 64 + lane];   // b128, conflict-free
                    const uint4 wb = wBu[p * 64 + lane];
                    #pragma unroll
                    for (int j = 0; j < 4; ++j) {
                        h2v t = u2h(wb.w);                 // bias pair
                        t = evR[j][0] * u2h(wa.x) + t;     // v_pk_fma_f16 (contract)
                        t = evR[j][1] * u2h(wa.y) + t;
                        t = evR[j][2] * u2h(wa.z) + t;
                        t = evR[j][3] * u2h(wa.w) + t;
                        t = evR[j][4] * u2h(wb.x) + t;
                        t = evR[j][5] * u2h(wb.y) + t;
                        t = evR[j][6] * u2h(wb.z) + t;
                        t = __builtin_elementwise_max(t, (h2v)((_Float16)0.f)); // v_pk_max
                        const unsigned xp = (pp == 0) ? xr[j].x : (pp == 1) ? xr[j].y
                                          : (pp == 2) ? xr[j].z : xr[j].w;
                        acc[half * 4 + j] = __builtin_amdgcn_fdot2(
                            t, u2h(xp), acc[half * 4 + j], false);
                    }
                }
            }
        }

        #pragma unroll
        for (int m = 0; m < MBX; ++m)
            atomicAdd(&agg[(size_t)sD[m] * HIDDEN_DIM + lane], acc[m]);
    }
}

// ---------------------------------------------------------------------------
// K_C v3: classifier as bf16 MFMA GEMM (verbatim, passing since round 4).
// ---------------------------------------------------------------------------
#define ASTRIDE 168
__global__ __launch_bounds__(256) void k_edge3(const int* __restrict__ ei,
                                               const float* __restrict__ ea,
                                               const float* __restrict__ agg,
                                               const ushort* __restrict__ bfrag,
                                               const float* __restrict__ w_e2,
                                               const float* __restrict__ b_e2,
                                               float* __restrict__ out) {
    __shared__ ushort aS[64 * ASTRIDE];   // 21504B
    __shared__ ushort bS[5 * 4 * 64 * 8]; // 20480B
    __shared__ float  w2S[128];
    {
        const uint4* g = (const uint4*)bfrag;
        uint4* s = (uint4*)bS;
        for (int t = threadIdx.x; t < 1280; t += 256) s[t] = g[t];
        if (threadIdx.x < 128) w2S[threadIdx.x] = w_e2[threadIdx.x];
    }
    const int e0 = blockIdx.x * 64;
    {
        const int el = threadIdx.x >> 2;
        const int q  = threadIdx.x & 3;
        const int e  = e0 + el;
        const int src = ei[e], dst = ei[NUM_EDGES + e];
        const float4* ps = (const float4*)(agg + (size_t)src * HIDDEN_DIM + q * 16);
        const float4* pd = (const float4*)(agg + (size_t)dst * HIDDEN_DIM + q * 16);
        unsigned* arow = (unsigned*)(aS + el * ASTRIDE);
        #pragma unroll
        for (int i = 0; i < 4; ++i) {
            float4 s = ps[i];
            arow[q * 8 + i * 2 + 0] = pack2bf(fmaxf(s.x, 0.f), fmaxf(s.y, 0.f));
            arow[q * 8 + i * 2 + 1] = pack2bf(fmaxf(s.z, 0.f), fmaxf(s.w, 0.f));
        }
        #pragma unroll
        for (int i = 0; i < 4; ++i) {
            float4 d = pd[i];
            arow[32 + q * 8 + i * 2 + 0] = pack2bf(fmaxf(d.x, 0.f), fmaxf(d.y, 0.f));
            arow[32 + q * 8 + i * 2 + 1] = pack2bf(fmaxf(d.z, 0.f), fmaxf(d.w, 0.f));
        }
        if (q == 0) {
            float ev[8];
            #pragma unroll
            for (int k = 0; k < EDGE_DIM; ++k) ev[k] = ea[e * EDGE_DIM + k];
            ev[7] = 1.0f;
            #pragma unroll
            for (int i = 0; i < 4; ++i)
                arow[64 + i] = pack2bf(ev[2 * i], ev[2 * i + 1]);
        } else {
            unsigned* z = arow + 64 + q * 4;
            z[0] = 0u; z[1] = 0u; z[2] = 0u; z[3] = 0u;
        }
    }
    __syncthreads();

    const int lane = threadIdx.x & 63;
    const int w    = threadIdx.x >> 6;
    f32x4 acc[4];
    #pragma unroll
    for (int nt = 0; nt < 4; ++nt) acc[nt] = (f32x4){0.f, 0.f, 0.f, 0.f};

    const ushort* arow = aS + (w * 16 + (lane & 15)) * ASTRIDE + (lane >> 4) * 8;
    #pragma unroll
    for (int ks = 0; ks < 5; ++ks) {
        bf16x8 af = *(const bf16x8*)(arow + ks * 32);
        #pragma unroll
        for (int nt = 0; nt < 4; ++nt) {
            bf16x8 bf = *(const bf16x8*)(bS + ((ks * 4 + nt) * 64 + lane) * 8);
            acc[nt] = __builtin_amdgcn_mfma_f32_16x16x32_bf16(af, bf, acc[nt], 0, 0, 0);
        }
    }

    float w20[4], w21[4];
    #pragma unroll
    for (int nt = 0; nt < 4; ++nt) {
        int o = nt * 16 + (lane & 15);
        w20[nt] = w2S[o * 2 + 0];
        w21[nt] = w2S[o * 2 + 1];
    }
    const float bias0 = b_e2[0], bias1 = b_e2[1];
    #pragma unroll
    for (int r = 0; r < 4; ++r) {
        float p0 = 0.f, p1 = 0.f;
        #pragma unroll
        for (int nt = 0; nt < 4; ++nt) {
            float z = fmaxf(acc[nt][r], 0.f);
            p0 = fmaf(z, w20[nt], p0);
            p1 = fmaf(z, w21[nt], p1);
        }
        #pragma unroll
        for (int off = 1; off < 16; off <<= 1) {
            p0 += __shfl_xor(p0, off);
            p1 += __shfl_xor(p1, off);
        }
        if ((lane & 15) == 0) {
            int e = e0 + w * 16 + (lane >> 4) * 4 + r;
            float2 v; v.x = p0 + bias0; v.y = p1 + bias1;
            ((float2*)out)[e] = v;
        }
    }
}

// ---------------------------------------------------------------------------
extern "C" void kernel_launch(void* const* d_in, const int* in_sizes, int n_in,
                              void* d_out, int out_size, void* d_ws, size_t ws_size,
                              hipStream_t stream) {
    const int*   ei        = (const int*)d_in[0];
    const float* edge_attr = (const float*)d_in[1];
    const float* node_emb  = (const float*)d_in[2];
    const float* w_nn      = (const float*)d_in[3];
    const float* b_nn      = (const float*)d_in[4];
    const float* root_w    = (const float*)d_in[5];
    const float* conv_bias = (const float*)d_in[6];
    const float* w_e1      = (const float*)d_in[7];
    const float* b_e1      = (const float*)d_in[8];
    const float* w_e2      = (const float*)d_in[9];
    const float* b_e2      = (const float*)d_in[10];
    float*       out       = (float*)d_out;
    float*       agg       = (float*)d_ws;                       // [N,64] f32 = 12.8 MB
    ushort*      bfrag     = (ushort*)((char*)d_ws + 12800000);  // 20480 B

    // K_IP: fused agg-init + classifier-fragment prep (one launch)
    k_initprep<<<INIT_BLOCKS + PREP_BLOCKS, 256, 0, stream>>>(
        node_emb, root_w, conv_bias, w_e1, b_e1, agg, bfrag);
    // K_B: fused edge-MLP (packed f16) + per-edge matvec + scatter-add
    k_msg10<<<1024, 512, 0, stream>>>(ei, edge_attr, node_emb, w_nn, b_nn, agg);
    // K_C: classifier GEMM
    k_edge3<<<NUM_EDGES / 64, 256, 0, stream>>>(ei, edge_attr, agg, bfrag, w_e2, b_e2, out);
}

// Round 18
// 118.480 us; speedup vs baseline: 1.0683x; 1.0157x over previous
//
#include <hip/hip_runtime.h>
#include <hip/hip_bf16.h>

#define NUM_NODES 50000
#define NODE_DIM 32
#define EDGE_DIM 7
#define HIDDEN_DIM 64
#define NUM_EDGES 200000

#define INIT_BLOCKS ((NUM_NODES + 127) / 128)        // 391
#define PREP_BLOCKS ((5 * 4 * 64 * 8 + 255) / 256)   // 40

typedef __attribute__((ext_vector_type(8))) short bf16x8;
typedef __attribute__((ext_vector_type(4))) float f32x4;
typedef _Float16 h2v __attribute__((ext_vector_type(2)));

__device__ inline unsigned f2bf(float f) {
    union { float f; unsigned u; } x; x.f = f;
    return (x.u + 0x7FFFu + ((x.u >> 16) & 1u)) >> 16;   // RNE
}
__device__ inline unsigned pack2bf(float a, float b) {
    return f2bf(a) | (f2bf(b) << 16);
}
__device__ inline h2v u2h(unsigned u) {
    union { unsigned u; h2v h; } c; c.u = u; return c.h;
}
__device__ inline unsigned h2u(h2v h) {
    union { h2v h; unsigned u; } c; c.h = h; return c.u;
}
__device__ inline unsigned packh2(float a, float b) {
    h2v h; h[0] = (_Float16)a; h[1] = (_Float16)b; return h2u(h);
}

// ---------------------------------------------------------------------------
// K_IP: fused init + prep (r17 structure). agg is now f16 [N][64] (6.4MB):
// init computes the root term in f32, packs channel pairs, even lanes store.
// ---------------------------------------------------------------------------
__global__ __launch_bounds__(256) void k_initprep(const float* __restrict__ x,
                                                  const float* __restrict__ root_w,
                                                  const float* __restrict__ conv_bias,
                                                  const float* __restrict__ w_e1,
                                                  const float* __restrict__ b_e1,
                                                  ushort* __restrict__ aggh,
                                                  ushort* __restrict__ bfrag) {
    if (blockIdx.x >= INIT_BLOCKS) {
        // ---- k_prep body (verified r4+) ----
        int u = (blockIdx.x - INIT_BLOCKS) * blockDim.x + threadIdx.x;
        if (u < 5 * 4 * 64 * 8) {
            int j     = u & 7;
            int lane  = (u >> 3) & 63;
            int ntile = (u >> 9) & 3;
            int kstep = u >> 11;
            int k = kstep * 32 + (lane >> 4) * 8 + j;
            int o = ntile * 16 + (lane & 15);
            float v = (k < 135) ? w_e1[k * 64 + o] : ((k == 135) ? b_e1[o] : 0.f);
            bfrag[u] = (ushort)f2bf(v);
        }
        return;
    }
    // ---- init body (verified r4+; f16-pair store new) ----
    __shared__ float rw[NODE_DIM * HIDDEN_DIM];   // 8KB
    __shared__ float cb[HIDDEN_DIM];
    __shared__ float xS[128 * NODE_DIM];          // 16KB
    for (int t = threadIdx.x; t < NODE_DIM * HIDDEN_DIM; t += 256) rw[t] = root_w[t];
    if (threadIdx.x < HIDDEN_DIM) cb[threadIdx.x] = conv_bias[threadIdx.x];
    const int nb = blockIdx.x * 128;
    {
        const float4* xg = (const float4*)x;
        float4* xs4 = (float4*)xS;
        #pragma unroll
        for (int r = 0; r < 4; ++r) {
            int t = r * 256 + threadIdx.x;
            int gi = nb * (NODE_DIM / 4) + t;
            xs4[t] = (gi < NUM_NODES * (NODE_DIM / 4)) ? xg[gi] : make_float4(0.f, 0.f, 0.f, 0.f);
        }
    }
    __syncthreads();
    const int lane = threadIdx.x & 63;
    const int w    = threadIdx.x >> 6;
    for (int r = 0; r < 32; ++r) {
        const int n = nb + w * 32 + r;
        if (n >= NUM_NODES) break;                 // wave-uniform
        float acc = cb[lane];
        const float* xr = &xS[(w * 32 + r) * NODE_DIM];
        #pragma unroll
        for (int i = 0; i < NODE_DIM; ++i)
            acc = fmaf(xr[i], rw[i * HIDDEN_DIM + lane], acc);
        const float nbr = __shfl_down(acc, 1);
        if (!(lane & 1))
            ((unsigned*)(aggh + (size_t)n * HIDDEN_DIM))[lane >> 1] = packh2(acc, nbr);
    }
}

// ---------------------------------------------------------------------------
// K_B v12: r15's packed-f16 MLP (best, 82.4 µs) + PACKED-F16 ATOMIC scatter.
// Atomic hypothesis test: 12.8M f32 RMWs -> 6.4M pk_add_f16 RMWs (51->25.6MB
// of L2 write traffic). Even lane packs (own, neighbor) channels via
// __shfl_down and issues one global_atomic_pk_add_f16 (inline asm — ISA
// path, no HIP fp16 wrapper dependence per r14 lesson).
// Everything upstream of the scatter is r15-verbatim.
// ---------------------------------------------------------------------------
#define MBX 8
__global__ __launch_bounds__(512) void k_msg12(const int* __restrict__ ei,
                                               const float* __restrict__ ea,
                                               const float* __restrict__ x,
                                               const float* __restrict__ w_nn,
                                               const float* __restrict__ b_nn,
                                               ushort* __restrict__ aggh) {
    __shared__ uint4    wAu[16 * 64];          // 16KB  (k0..k3 pairs)
    __shared__ uint4    wBu[16 * 64];          // 16KB  (k4..k6 + bias pairs)
    __shared__ unsigned xHu[8][MBX][16];       // 4KB   (h2v i-pairs)
    __shared__ float    eS[8][MBX][8];         // 2KB
    for (int c = threadIdx.x; c < 16 * 64; c += 512) {
        const int p = c >> 6, o = c & 63;
        const int c0 = (2 * p) * 64 + o, c1 = c0 + 64;
        uint4 a, b;
        a.x = packh2(w_nn[c0],            w_nn[c1]);
        a.y = packh2(w_nn[2048 + c0],     w_nn[2048 + c1]);
        a.z = packh2(w_nn[2 * 2048 + c0], w_nn[2 * 2048 + c1]);
        a.w = packh2(w_nn[3 * 2048 + c0], w_nn[3 * 2048 + c1]);
        b.x = packh2(w_nn[4 * 2048 + c0], w_nn[4 * 2048 + c1]);
        b.y = packh2(w_nn[5 * 2048 + c0], w_nn[5 * 2048 + c1]);
        b.z = packh2(w_nn[6 * 2048 + c0], w_nn[6 * 2048 + c1]);
        b.w = packh2(b_nn[c0],            b_nn[c1]);
        wAu[c] = a; wBu[c] = b;
    }
    __syncthreads();

    const int lane   = threadIdx.x & 63;
    const int ws     = threadIdx.x >> 6;
    const int wave   = (blockIdx.x * blockDim.x + threadIdx.x) >> 6;
    const int nwaves = (gridDim.x * blockDim.x) >> 6;

    for (int e0 = wave * MBX; e0 < NUM_EDGES; e0 += nwaves * MBX) {
        // NUM_EDGES % 8 == 0, no tail.
        int sD[MBX];
        #pragma unroll
        for (int m = 0; m < MBX; ++m)
            sD[m] = __builtin_amdgcn_readfirstlane(ei[NUM_EDGES + e0 + m]);

        // stage x rows as packed h2v i-pairs + ea floats (r15-verbatim)
        {
            const int m  = lane >> 3;
            const int q4 = lane & 7;
            const int s  = ei[e0 + m];
            const float4 xv = *(const float4*)(x + (size_t)s * NODE_DIM + q4 * 4);
            xHu[ws][m][2 * q4 + 0] = packh2(xv.x, xv.y);
            xHu[ws][m][2 * q4 + 1] = packh2(xv.z, xv.w);
            if (lane < MBX * EDGE_DIM)
                eS[ws][lane / EDGE_DIM][lane % EDGE_DIM] = ea[(size_t)e0 * EDGE_DIM + lane];
        }
        // wave-coherent LDS write->read; compiler inserts waits (r2-r4 proven).

        float acc[MBX];
        #pragma unroll
        for (int m = 0; m < MBX; ++m) acc[m] = 0.f;

        #pragma unroll
        for (int half = 0; half < 2; ++half) {
            // replicated ea per-k for 4 edges (28 VGPR)
            h2v evR[4][7];
            #pragma unroll
            for (int j = 0; j < 4; ++j) {
                const float4* e4 = (const float4*)&eS[ws][half * 4 + j][0];
                const float4 a0 = e4[0], a1 = e4[1];   // a1.w unused
                evR[j][0] = (h2v)((_Float16)a0.x);
                evR[j][1] = (h2v)((_Float16)a0.y);
                evR[j][2] = (h2v)((_Float16)a0.z);
                evR[j][3] = (h2v)((_Float16)a0.w);
                evR[j][4] = (h2v)((_Float16)a1.x);
                evR[j][5] = (h2v)((_Float16)a1.y);
                evR[j][6] = (h2v)((_Float16)a1.z);
            }

            #pragma unroll 2
            for (int p4 = 0; p4 < 4; ++p4) {
                uint4 xr[4];
                #pragma unroll
                for (int j = 0; j < 4; ++j)
                    xr[j] = *(const uint4*)&xHu[ws][half * 4 + j][p4 * 4];  // b128 broadcast
                #pragma unroll
                for (int pp = 0; pp < 4; ++pp) {
                    const int p = p4 * 4 + pp;
                    const uint4 wa = wAu[p * 64 + lane];   // b128, conflict-free
                    const uint4 wb = wBu[p * 64 + lane];
                    #pragma unroll
                    for (int j = 0; j < 4; ++j) {
                        h2v t = u2h(wb.w);                 // bias pair
                        t = evR[j][0] * u2h(wa.x) + t;     // v_pk_fma_f16 (contract)
                        t = evR[j][1] * u2h(wa.y) + t;
                        t = evR[j][2] * u2h(wa.z) + t;
                        t = evR[j][3] * u2h(wa.w) + t;
                        t = evR[j][4] * u2h(wb.x) + t;
                        t = evR[j][5] * u2h(wb.y) + t;
                        t = evR[j][6] * u2h(wb.z) + t;
                        t = __builtin_elementwise_max(t, (h2v)((_Float16)0.f)); // v_pk_max
                        const unsigned xp = (pp == 0) ? xr[j].x : (pp == 1) ? xr[j].y
                                          : (pp == 2) ? xr[j].z : xr[j].w;
                        acc[half * 4 + j] = __builtin_amdgcn_fdot2(
                            t, u2h(xp), acc[half * 4 + j], false);
                    }
                }
            }
        }

        // packed-f16 atomic scatter: even lane adds (ch lane, ch lane+1)
        #pragma unroll
        for (int m = 0; m < MBX; ++m) {
            const float nbr = __shfl_down(acc[m], 1);
            if (!(lane & 1)) {
                const unsigned pk = packh2(acc[m], nbr);
                ushort* ap = aggh + (size_t)sD[m] * HIDDEN_DIM + lane;  // 4B-aligned
                asm volatile("global_atomic_pk_add_f16 %0, %1, off"
                             :: "v"(ap), "v"(pk) : "memory");
            }
        }
    }
}

// ---------------------------------------------------------------------------
// K_C v4: classifier bf16 MFMA GEMM (r4+ structure); agg gather now f16
// (halved L2 traffic), converted+relu'd+bf16-packed during A-tile staging.
// ---------------------------------------------------------------------------
#define ASTRIDE 168
__global__ __launch_bounds__(256) void k_edge3(const int* __restrict__ ei,
                                               const float* __restrict__ ea,
                                               const ushort* __restrict__ aggh,
                                               const ushort* __restrict__ bfrag,
                                               const float* __restrict__ w_e2,
                                               const float* __restrict__ b_e2,
                                               float* __restrict__ out) {
    __shared__ ushort aS[64 * ASTRIDE];   // 21504B
    __shared__ ushort bS[5 * 4 * 64 * 8]; // 20480B
    __shared__ float  w2S[128];
    {
        const uint4* g = (const uint4*)bfrag;
        uint4* s = (uint4*)bS;
        for (int t = threadIdx.x; t < 1280; t += 256) s[t] = g[t];
        if (threadIdx.x < 128) w2S[threadIdx.x] = w_e2[threadIdx.x];
    }
    const int e0 = blockIdx.x * 64;
    {
        const int el = threadIdx.x >> 2;
        const int q  = threadIdx.x & 3;
        const int e  = e0 + el;
        const int src = ei[e], dst = ei[NUM_EDGES + e];
        const uint4* ps = (const uint4*)(aggh + (size_t)src * HIDDEN_DIM + q * 16); // 2 uint4
        const uint4* pd = (const uint4*)(aggh + (size_t)dst * HIDDEN_DIM + q * 16);
        unsigned* arow = (unsigned*)(aS + el * ASTRIDE);
        #pragma unroll
        for (int i = 0; i < 2; ++i) {
            const uint4 sv = ps[i];
            const unsigned uu[4] = {sv.x, sv.y, sv.z, sv.w};
            #pragma unroll
            for (int jj = 0; jj < 4; ++jj) {
                h2v hh = u2h(uu[jj]);
                arow[q * 8 + i * 4 + jj] =
                    pack2bf(fmaxf((float)hh[0], 0.f), fmaxf((float)hh[1], 0.f));
            }
        }
        #pragma unroll
        for (int i = 0; i < 2; ++i) {
            const uint4 dv = pd[i];
            const unsigned uu[4] = {dv.x, dv.y, dv.z, dv.w};
            #pragma unroll
            for (int jj = 0; jj < 4; ++jj) {
                h2v hh = u2h(uu[jj]);
                arow[32 + q * 8 + i * 4 + jj] =
                    pack2bf(fmaxf((float)hh[0], 0.f), fmaxf((float)hh[1], 0.f));
            }
        }
        if (q == 0) {
            float ev[8];
            #pragma unroll
            for (int k = 0; k < EDGE_DIM; ++k) ev[k] = ea[e * EDGE_DIM + k];
            ev[7] = 1.0f;
            #pragma unroll
            for (int i = 0; i < 4; ++i)
                arow[64 + i] = pack2bf(ev[2 * i], ev[2 * i + 1]);
        } else {
            unsigned* z = arow + 64 + q * 4;
            z[0] = 0u; z[1] = 0u; z[2] = 0u; z[3] = 0u;
        }
    }
    __syncthreads();

    const int lane = threadIdx.x & 63;
    const int w    = threadIdx.x >> 6;
    f32x4 acc[4];
    #pragma unroll
    for (int nt = 0; nt < 4; ++nt) acc[nt] = (f32x4){0.f, 0.f, 0.f, 0.f};

    const ushort* arow = aS + (w * 16 + (lane & 15)) * ASTRIDE + (lane >> 4) * 8;
    #pragma unroll
    for (int ks = 0; ks < 5; ++ks) {
        bf16x8 af = *(const bf16x8*)(arow + ks * 32);
        #pragma unroll
        for (int nt = 0; nt < 4; ++nt) {
            bf16x8 bf = *(const bf16x8*)(bS + ((ks * 4 + nt) * 64 + lane) * 8);
            acc[nt] = __builtin_amdgcn_mfma_f32_16x16x32_bf16(af, bf, acc[nt], 0, 0, 0);
        }
    }

    float w20[4], w21[4];
    #pragma unroll
    for (int nt = 0; nt < 4; ++nt) {
        int o = nt * 16 + (lane & 15);
        w20[nt] = w2S[o * 2 + 0];
        w21[nt] = w2S[o * 2 + 1];
    }
    const float bias0 = b_e2[0], bias1 = b_e2[1];
    #pragma unroll
    for (int r = 0; r < 4; ++r) {
        float p0 = 0.f, p1 = 0.f;
        #pragma unroll
        for (int nt = 0; nt < 4; ++nt) {
            float z = fmaxf(acc[nt][r], 0.f);
            p0 = fmaf(z, w20[nt], p0);
            p1 = fmaf(z, w21[nt], p1);
        }
        #pragma unroll
        for (int off = 1; off < 16; off <<= 1) {
            p0 += __shfl_xor(p0, off);
            p1 += __shfl_xor(p1, off);
        }
        if ((lane & 15) == 0) {
            int e = e0 + w * 16 + (lane >> 4) * 4 + r;
            float2 v; v.x = p0 + bias0; v.y = p1 + bias1;
            ((float2*)out)[e] = v;
        }
    }
}

// ---------------------------------------------------------------------------
extern "C" void kernel_launch(void* const* d_in, const int* in_sizes, int n_in,
                              void* d_out, int out_size, void* d_ws, size_t ws_size,
                              hipStream_t stream) {
    const int*   ei        = (const int*)d_in[0];
    const float* edge_attr = (const float*)d_in[1];
    const float* node_emb  = (const float*)d_in[2];
    const float* w_nn      = (const float*)d_in[3];
    const float* b_nn      = (const float*)d_in[4];
    const float* root_w    = (const float*)d_in[5];
    const float* conv_bias = (const float*)d_in[6];
    const float* w_e1      = (const float*)d_in[7];
    const float* b_e1      = (const float*)d_in[8];
    const float* w_e2      = (const float*)d_in[9];
    const float* b_e2      = (const float*)d_in[10];
    float*       out       = (float*)d_out;
    ushort*      aggh      = (ushort*)d_ws;                      // [N,64] f16 = 6.4 MB
    ushort*      bfrag     = (ushort*)((char*)d_ws + 12800000);  // 20480 B (offset unchanged)

    // K_IP: fused agg-init (f16 pairs) + classifier-fragment prep
    k_initprep<<<INIT_BLOCKS + PREP_BLOCKS, 256, 0, stream>>>(
        node_emb, root_w, conv_bias, w_e1, b_e1, aggh, bfrag);
    // K_B: fused edge-MLP (packed f16) + matvec + packed-f16 atomic scatter
    k_msg12<<<1024, 512, 0, stream>>>(ei, edge_attr, node_emb, w_nn, b_nn, aggh);
    // K_C: classifier GEMM (f16 agg gather)
    k_edge3<<<NUM_EDGES / 64, 256, 0, stream>>>(ei, edge_attr, aggh, bfrag, w_e2, b_e2, out);
}